// Round 14
// baseline (214.902 us; speedup 1.0000x reference)
//
#include <hip/hip_runtime.h>
#include <hip/hip_fp16.h>

constexpr int H = 64;
constexpr int PAD = 68;     // LDS row stride (floats) for MLP tiles
constexpr int BSH = 6;      // 64 nodes per bucket
constexpr int EPB = 4096;   // edges per binning block
constexpr int EPT = EPB / 256;  // 16 edges per thread

__device__ inline unsigned pack2(float a, float b) {
    __half2 hh = __floats2half2_rn(a, b);
    return *(unsigned*)&hh;
}
__device__ inline float2 up2(unsigned u) {
    __half2 hh = *(__half2*)&u;
    return __half22float2(hh);
}

// ---------------- encode: h16[n][j] = x[n]*ne_w[j]+ne_b[j]; also zeroes scratch
__global__ __launch_bounds__(256) void encode_kernel(
    const float* __restrict__ x, const float* __restrict__ nw,
    const float* __restrict__ nb, __half* __restrict__ hout, int N,
    unsigned* __restrict__ zp, int zn)
{
    int idx = blockIdx.x * 256 + threadIdx.x;
    if (idx < zn) zp[idx] = 0u;               // fused zero of sums/counts/ghist
    if (idx >= N * 16) return;
    int n = idx >> 4, c = idx & 15;
    float xv = x[n];
    float4 w = ((const float4*)nw)[c];
    float4 b = ((const float4*)nb)[c];
    uint2 r;
    r.x = pack2(fmaf(xv, w.x, b.x), fmaf(xv, w.y, b.y));
    r.y = pack2(fmaf(xv, w.z, b.z), fmaf(xv, w.w, b.w));
    ((uint2*)hout)[idx] = r;
}

// ---------------- bucket histogram (LDS-aggregated) ----------------
__global__ __launch_bounds__(256) void bhist_kernel(
    const int* __restrict__ ei, int* __restrict__ ghist, int E, int NB)
{
    extern __shared__ int lh[];               // NB ints
    for (int b = threadIdx.x; b < NB; b += 256) lh[b] = 0;
    __syncthreads();
    int k0 = blockIdx.x * EPB;
#pragma unroll
    for (int i = 0; i < EPT; ++i) {
        int k = k0 + threadIdx.x + i * 256;
        if (k < E) atomicAdd(&lh[ei[E + k] >> BSH], 1);
    }
    __syncthreads();
    for (int b = threadIdx.x; b < NB; b += 256)
        if (lh[b]) atomicAdd(&ghist[b], lh[b]);
}

// ---------------- single-block exclusive scan; also seeds gcur ----------------
__global__ __launch_bounds__(256) void bscan_kernel(
    const int* __restrict__ ghist, int* __restrict__ off,
    int* __restrict__ gcur, int NB)
{
    __shared__ int part[256];
    int t = threadIdx.x;
    const int C = (NB + 255) / 256;
    int loc[16];
    int s = 0;
    for (int j = 0; j < C; ++j) {
        int idx = t * C + j;
        int v = (idx < NB) ? ghist[idx] : 0;
        loc[j] = s; s += v;
    }
    part[t] = s;
    __syncthreads();
    for (int d = 1; d < 256; d <<= 1) {
        int x = (t >= d) ? part[t - d] : 0;
        __syncthreads();
        part[t] += x;
        __syncthreads();
    }
    int base = part[t] - s;
    for (int j = 0; j < C; ++j) {
        int idx = t * C + j;
        if (idx < NB) { int v = base + loc[j]; off[idx] = v; gcur[idx] = v; }
    }
    if (t == 255) off[NB] = part[255];
}

// ---------------- block-aggregated bin scatter ----------------
// Record: (dstLocal<<17 | src, ea) -- src < 2^17, dl < 64.
__global__ __launch_bounds__(256) void binscatter_kernel(
    const int* __restrict__ ei, const float* __restrict__ eattr,
    int* __restrict__ gcur, int2* __restrict__ bed, int E, int NB)
{
    extern __shared__ int smem[];
    int2* stage = (int2*)smem;                // EPB int2
    int*  A     = smem + 2 * EPB;             // NB+1
    int*  B     = A + NB + 1;                 // NB
    int*  part  = B + NB;                     // 256
    int t = threadIdx.x;
    int k0 = blockIdx.x * EPB;

    for (int b = t; b < NB + 1; b += 256) A[b] = 0;
    __syncthreads();

    int dsts[EPT];
#pragma unroll
    for (int i = 0; i < EPT; ++i) {
        int k = k0 + t + i * 256;
        dsts[i] = (k < E) ? ei[E + k] : -1;
        if (dsts[i] >= 0) atomicAdd(&A[dsts[i] >> BSH], 1);
    }
    __syncthreads();

    const int C = (NB + 255) / 256;
    int loc[16];
    int s = 0;
    for (int j = 0; j < C; ++j) {
        int idx = t * C + j;
        int v = (idx < NB) ? A[idx] : 0;
        loc[j] = s; s += v;
    }
    part[t] = s;
    __syncthreads();
    for (int d = 1; d < 256; d <<= 1) {
        int x = (t >= d) ? part[t - d] : 0;
        __syncthreads();
        part[t] += x;
        __syncthreads();
    }
    int base = part[t] - s;
    int tot = part[255];
    for (int j = 0; j < C; ++j) {
        int idx = t * C + j;
        if (idx < NB) { int e = base + loc[j]; A[idx] = e; B[idx] = e; }
    }
    if (t == 255) A[NB] = tot;
    __syncthreads();

#pragma unroll
    for (int i = 0; i < EPT; ++i) {
        if (dsts[i] >= 0) {
            int k = k0 + t + i * 256;
            int b = dsts[i] >> BSH;
            int dl = dsts[i] & 63;
            int slot = atomicAdd(&B[b], 1);
            stage[slot] = make_int2((dl << 17) | ei[k], __float_as_int(eattr[k]));
        }
    }
    __syncthreads();

    for (int b = t; b < NB; b += 256) {
        int c0 = A[b], c1 = B[b];
        if (c1 > c0) B[b] = atomicAdd(&gcur[b], c1 - c0) - c0;
    }
    __syncthreads();

    int s0 = t * EPT;
    int lo = 0, hi = NB;
    while (hi - lo > 1) { int mid = (lo + hi) >> 1; if (A[mid] <= s0) lo = mid; else hi = mid; }
    int b = lo;
#pragma unroll
    for (int i = 0; i < EPT; ++i) {
        int sl = s0 + i;
        if (sl >= tot) break;
        while (sl >= A[b + 1]) ++b;
        bed[B[b] + sl] = stage[sl];
    }
}

// ---------------- per-bucket dl counting-sort -> exact per-node CSR ----------
// Oversize fallback (unreachable at this E/NB) marks nend = ~e1 (negative).
__global__ __launch_bounds__(256) void dlsort_kernel(
    int2* __restrict__ bed, const int* __restrict__ off,
    int* __restrict__ nstart, int* __restrict__ nend, int N, int NB)
{
    __shared__ int2 stage[4096];
    __shared__ int hist[64], excl[65], cur[64];
    int t = threadIdx.x, b = blockIdx.x;
    int e0 = off[b], e1 = off[b + 1], cnt = e1 - e0;
    if (t < 64) hist[t] = 0;
    __syncthreads();

    if (cnt <= 4096) {
        for (int i = t; i < cnt; i += 256) {
            int2 r = bed[e0 + i];
            stage[i] = r;
            atomicAdd(&hist[(unsigned)r.x >> 17], 1);
        }
        __syncthreads();
        if (t == 0) {
            int s = 0;
#pragma unroll
            for (int i = 0; i < 64; ++i) { excl[i] = s; s += hist[i]; }
            excl[64] = s;
        }
        __syncthreads();
        if (t < 64) {
            cur[t] = excl[t];
            int n = b * 64 + t;
            if (n < N) { nstart[n] = e0 + excl[t]; nend[n] = e0 + excl[t + 1]; }
        }
        __syncthreads();
        for (int i = t; i < cnt; i += 256) {
            int2 r = stage[i];
            int p = atomicAdd(&cur[(unsigned)r.x >> 17], 1);
            bed[e0 + p] = r;
        }
    } else {
        int n = b * 64 + t;
        if (t < 64 && n < N) { nstart[n] = e0; nend[n] = ~e1; }  // masked marker
    }
}

// ---------------- gather v5 (proven): wave/node, masked-16-burst --------------
__global__ __launch_bounds__(256) void gather_kernel(
    const __half* __restrict__ h, const int2* __restrict__ bed,
    const int* __restrict__ nstart, const int* __restrict__ nend,
    const float* __restrict__ ew, const float* __restrict__ eb,
    __half* __restrict__ z, int N)
{
    int lane = threadIdx.x & 63;
    int wid  = threadIdx.x >> 6;
    int n = blockIdx.x * 4 + wid;
    if (n >= N) return;
    float wj = ew[lane], bj = eb[lane];
    int e  = nstart[n];
    int e1 = nend[n];
    float acc = __half2float(h[(size_t)n * H + lane]);   // self term (eps = 0)

    if (e1 >= 0) {
        while (e1 - e > 16) {
            const int2* p = bed + __builtin_amdgcn_readfirstlane(e);
            int2 r0 = p[0], r1 = p[1], r2 = p[2], r3 = p[3];
            int2 r4 = p[4], r5 = p[5], r6 = p[6], r7 = p[7];
            float v0 = __half2float(h[(size_t)(r0.x & 0x1FFFF) * H + lane]);
            float v1 = __half2float(h[(size_t)(r1.x & 0x1FFFF) * H + lane]);
            float v2 = __half2float(h[(size_t)(r2.x & 0x1FFFF) * H + lane]);
            float v3 = __half2float(h[(size_t)(r3.x & 0x1FFFF) * H + lane]);
            float v4 = __half2float(h[(size_t)(r4.x & 0x1FFFF) * H + lane]);
            float v5 = __half2float(h[(size_t)(r5.x & 0x1FFFF) * H + lane]);
            float v6 = __half2float(h[(size_t)(r6.x & 0x1FFFF) * H + lane]);
            float v7 = __half2float(h[(size_t)(r7.x & 0x1FFFF) * H + lane]);
            acc += fmaxf(fmaf(__int_as_float(r0.y), wj, bj) + v0, 0.f)
                 + fmaxf(fmaf(__int_as_float(r1.y), wj, bj) + v1, 0.f)
                 + fmaxf(fmaf(__int_as_float(r2.y), wj, bj) + v2, 0.f)
                 + fmaxf(fmaf(__int_as_float(r3.y), wj, bj) + v3, 0.f)
                 + fmaxf(fmaf(__int_as_float(r4.y), wj, bj) + v4, 0.f)
                 + fmaxf(fmaf(__int_as_float(r5.y), wj, bj) + v5, 0.f)
                 + fmaxf(fmaf(__int_as_float(r6.y), wj, bj) + v6, 0.f)
                 + fmaxf(fmaf(__int_as_float(r7.y), wj, bj) + v7, 0.f);
            e += 8;
        }
        int r = e1 - e;
        const int2* p = bed + __builtin_amdgcn_readfirstlane(e);
        int2 q0 = p[0],  q1 = p[1],  q2 = p[2],  q3 = p[3];
        int2 q4 = p[4],  q5 = p[5],  q6 = p[6],  q7 = p[7];
        int2 q8 = p[8],  q9 = p[9],  qA = p[10], qB = p[11];
        int2 qC = p[12], qD = p[13], qE = p[14], qF = p[15];
        int s0 = (0  < r) ? (q0.x & 0x1FFFF) : 0;
        int s1 = (1  < r) ? (q1.x & 0x1FFFF) : 0;
        int s2 = (2  < r) ? (q2.x & 0x1FFFF) : 0;
        int s3 = (3  < r) ? (q3.x & 0x1FFFF) : 0;
        int s4 = (4  < r) ? (q4.x & 0x1FFFF) : 0;
        int s5 = (5  < r) ? (q5.x & 0x1FFFF) : 0;
        int s6 = (6  < r) ? (q6.x & 0x1FFFF) : 0;
        int s7 = (7  < r) ? (q7.x & 0x1FFFF) : 0;
        int s8 = (8  < r) ? (q8.x & 0x1FFFF) : 0;
        int s9 = (9  < r) ? (q9.x & 0x1FFFF) : 0;
        int sA = (10 < r) ? (qA.x & 0x1FFFF) : 0;
        int sB = (11 < r) ? (qB.x & 0x1FFFF) : 0;
        int sC = (12 < r) ? (qC.x & 0x1FFFF) : 0;
        int sD = (13 < r) ? (qD.x & 0x1FFFF) : 0;
        int sE = (14 < r) ? (qE.x & 0x1FFFF) : 0;
        int sF = (15 < r) ? (qF.x & 0x1FFFF) : 0;
        float v0 = __half2float(h[(size_t)s0 * H + lane]);
        float v1 = __half2float(h[(size_t)s1 * H + lane]);
        float v2 = __half2float(h[(size_t)s2 * H + lane]);
        float v3 = __half2float(h[(size_t)s3 * H + lane]);
        float v4 = __half2float(h[(size_t)s4 * H + lane]);
        float v5 = __half2float(h[(size_t)s5 * H + lane]);
        float v6 = __half2float(h[(size_t)s6 * H + lane]);
        float v7 = __half2float(h[(size_t)s7 * H + lane]);
        float v8 = __half2float(h[(size_t)s8 * H + lane]);
        float v9 = __half2float(h[(size_t)s9 * H + lane]);
        float vA = __half2float(h[(size_t)sA * H + lane]);
        float vB = __half2float(h[(size_t)sB * H + lane]);
        float vC = __half2float(h[(size_t)sC * H + lane]);
        float vD = __half2float(h[(size_t)sD * H + lane]);
        float vE = __half2float(h[(size_t)sE * H + lane]);
        float vF = __half2float(h[(size_t)sF * H + lane]);
        float m;
        m = fmaxf(fmaf(__int_as_float(q0.y), wj, bj) + v0, 0.f); acc += (0  < r) ? m : 0.f;
        m = fmaxf(fmaf(__int_as_float(q1.y), wj, bj) + v1, 0.f); acc += (1  < r) ? m : 0.f;
        m = fmaxf(fmaf(__int_as_float(q2.y), wj, bj) + v2, 0.f); acc += (2  < r) ? m : 0.f;
        m = fmaxf(fmaf(__int_as_float(q3.y), wj, bj) + v3, 0.f); acc += (3  < r) ? m : 0.f;
        m = fmaxf(fmaf(__int_as_float(q4.y), wj, bj) + v4, 0.f); acc += (4  < r) ? m : 0.f;
        m = fmaxf(fmaf(__int_as_float(q5.y), wj, bj) + v5, 0.f); acc += (5  < r) ? m : 0.f;
        m = fmaxf(fmaf(__int_as_float(q6.y), wj, bj) + v6, 0.f); acc += (6  < r) ? m : 0.f;
        m = fmaxf(fmaf(__int_as_float(q7.y), wj, bj) + v7, 0.f); acc += (7  < r) ? m : 0.f;
        m = fmaxf(fmaf(__int_as_float(q8.y), wj, bj) + v8, 0.f); acc += (8  < r) ? m : 0.f;
        m = fmaxf(fmaf(__int_as_float(q9.y), wj, bj) + v9, 0.f); acc += (9  < r) ? m : 0.f;
        m = fmaxf(fmaf(__int_as_float(qA.y), wj, bj) + vA, 0.f); acc += (10 < r) ? m : 0.f;
        m = fmaxf(fmaf(__int_as_float(qB.y), wj, bj) + vB, 0.f); acc += (11 < r) ? m : 0.f;
        m = fmaxf(fmaf(__int_as_float(qC.y), wj, bj) + vC, 0.f); acc += (12 < r) ? m : 0.f;
        m = fmaxf(fmaf(__int_as_float(qD.y), wj, bj) + vD, 0.f); acc += (13 < r) ? m : 0.f;
        m = fmaxf(fmaf(__int_as_float(qE.y), wj, bj) + vE, 0.f); acc += (14 < r) ? m : 0.f;
        m = fmaxf(fmaf(__int_as_float(qF.y), wj, bj) + vF, 0.f); acc += (15 < r) ? m : 0.f;
    } else {
        int ef = ~e1;
        unsigned mydl = (unsigned)(n & 63);
        for (int ee = e; ee < ef; ++ee) {
            int2 r = bed[ee];
            float v = __half2float(h[(size_t)(r.x & 0x1FFFF) * H + lane]);
            float m = fmaxf(fmaf(__int_as_float(r.y), wj, bj) + v, 0.f);
            acc += (((unsigned)r.x >> 17) == mydl) ? m : 0.f;
        }
    }
    z[(size_t)n * H + lane] = __float2half(acc);
}

// ---------------- per 64-node tile MLP (conflict-free LDS) -------------------
// Staging: wave w owns rows ic=w*16..+15, lane = node -> write bank (4i+n)%32,
// n spans 64 -> 2-way = free. uT writeback: float4 over p with XOR swizzle
// n0^((j>>3&3)<<2) -> colliding same-parity lanes spread over 4 bank spans.
__global__ __launch_bounds__(256) void mlp_kernel(
    const __half* __restrict__ z, const float* __restrict__ w1,
    const float* __restrict__ b1, const float* __restrict__ w2,
    const float* __restrict__ b2, __half* __restrict__ out,
    const int* __restrict__ batch, float* __restrict__ sums,
    float* __restrict__ counts, int N, int doPool)
{
    __shared__ float zT[H * PAD];
    __shared__ float wS[H * PAD];
    __shared__ int bseg[64];
    int tid = threadIdx.x;
    int nb = blockIdx.x * 64;

    {
        int i  = tid >> 2;
        int jc = (tid & 3) * 16;
        const float4* s = (const float4*)(w1 + i * H + jc);
        float4* d = (float4*)(wS + i * PAD + jc);
        d[0] = s[0]; d[1] = s[1]; d[2] = s[2]; d[3] = s[3];
    }
    if (doPool && tid < 64) bseg[tid] = (nb + tid < N) ? batch[nb + tid] : -1;
    {
        // conflict-free transpose staging: lane = node, wave = 16-row strip
        int n  = tid & 63;
        int ic = (tid >> 6) * 16;
        int node = nb + n;
        if (node < N) {
            const uint4* zr = (const uint4*)(z + (size_t)node * H + ic);
            uint4 u0 = zr[0], u1 = zr[1];          // 16 halves
            float2 f;
            f = up2(u0.x); zT[(ic+ 0)*PAD+n]=f.x; zT[(ic+ 1)*PAD+n]=f.y;
            f = up2(u0.y); zT[(ic+ 2)*PAD+n]=f.x; zT[(ic+ 3)*PAD+n]=f.y;
            f = up2(u0.z); zT[(ic+ 4)*PAD+n]=f.x; zT[(ic+ 5)*PAD+n]=f.y;
            f = up2(u0.w); zT[(ic+ 6)*PAD+n]=f.x; zT[(ic+ 7)*PAD+n]=f.y;
            f = up2(u1.x); zT[(ic+ 8)*PAD+n]=f.x; zT[(ic+ 9)*PAD+n]=f.y;
            f = up2(u1.y); zT[(ic+10)*PAD+n]=f.x; zT[(ic+11)*PAD+n]=f.y;
            f = up2(u1.z); zT[(ic+12)*PAD+n]=f.x; zT[(ic+13)*PAD+n]=f.y;
            f = up2(u1.w); zT[(ic+14)*PAD+n]=f.x; zT[(ic+15)*PAD+n]=f.y;
        } else {
#pragma unroll
            for (int m = 0; m < 16; ++m)
                zT[(ic + m) * PAD + n] = 0.f;
        }
    }
    __syncthreads();

    int tj = tid & 15, tn = tid >> 4;
    int j0 = tj * 4, n0 = tn * 4;

    float acc[4][4] = {};
#pragma unroll 4
    for (int i = 0; i < H; ++i) {
        float4 a = *(const float4*)(zT + i * PAD + n0);
        float4 b = *(const float4*)(wS + i * PAD + j0);
        float av[4] = {a.x, a.y, a.z, a.w};
        float bv[4] = {b.x, b.y, b.z, b.w};
#pragma unroll
        for (int p = 0; p < 4; ++p)
#pragma unroll
            for (int q = 0; q < 4; ++q)
                acc[p][q] = fmaf(av[p], bv[q], acc[p][q]);
    }
    float4 bb1 = *(const float4*)(b1 + j0);
    float u[4][4];
#pragma unroll
    for (int p = 0; p < 4; ++p) {
        u[p][0] = fmaxf(acc[p][0] + bb1.x, 0.f);
        u[p][1] = fmaxf(acc[p][1] + bb1.y, 0.f);
        u[p][2] = fmaxf(acc[p][2] + bb1.z, 0.f);
        u[p][3] = fmaxf(acc[p][3] + bb1.w, 0.f);
    }
    __syncthreads();

    // uT writeback: float4 over p, XOR-swizzled n to spread banks
#pragma unroll
    for (int q = 0; q < 4; ++q) {
        int j = j0 + q;
        int ns = n0 ^ (((j >> 3) & 3) << 2);
        float4 v = make_float4(u[0][q], u[1][q], u[2][q], u[3][q]);
        *(float4*)(zT + j * PAD + ns) = v;
    }
    {
        int i  = tid >> 2;
        int jc = (tid & 3) * 16;
        const float4* s = (const float4*)(w2 + i * H + jc);
        float4* d = (float4*)(wS + i * PAD + jc);
        d[0] = s[0]; d[1] = s[1]; d[2] = s[2]; d[3] = s[3];
    }
    __syncthreads();

    float acc2[4][4] = {};
#pragma unroll 4
    for (int i = 0; i < H; ++i) {
        int ns = n0 ^ (((i >> 3) & 3) << 2);
        float4 a = *(const float4*)(zT + i * PAD + ns);
        float4 b = *(const float4*)(wS + i * PAD + j0);
        float av[4] = {a.x, a.y, a.z, a.w};
        float bv[4] = {b.x, b.y, b.z, b.w};
#pragma unroll
        for (int p = 0; p < 4; ++p)
#pragma unroll
            for (int q = 0; q < 4; ++q)
                acc2[p][q] = fmaf(av[p], bv[q], acc2[p][q]);
    }
    float4 bb2 = *(const float4*)(b2 + j0);

    if (!doPool) {
#pragma unroll
        for (int p = 0; p < 4; ++p) {
            int n = nb + n0 + p;
            if (n < N) {
                uint2 r;
                r.x = pack2(fmaxf(acc2[p][0] + bb2.x, 0.f),
                            fmaxf(acc2[p][1] + bb2.y, 0.f));
                r.y = pack2(fmaxf(acc2[p][2] + bb2.z, 0.f),
                            fmaxf(acc2[p][3] + bb2.w, 0.f));
                *(uint2*)(out + (size_t)n * H + j0) = r;
            }
        }
    } else {
        __syncthreads();                    // all matmul2 zT reads done
#pragma unroll
        for (int p = 0; p < 4; ++p) {
            zT[(n0 + p) * PAD + j0 + 0] = fmaxf(acc2[p][0] + bb2.x, 0.f);
            zT[(n0 + p) * PAD + j0 + 1] = fmaxf(acc2[p][1] + bb2.y, 0.f);
            zT[(n0 + p) * PAD + j0 + 2] = fmaxf(acc2[p][2] + bb2.z, 0.f);
            zT[(n0 + p) * PAD + j0 + 3] = fmaxf(acc2[p][3] + bb2.w, 0.f);
        }
        __syncthreads();
        if (tid < 64) {                     // wave 0: segment pool from LDS
            int j = tid;
            float acc0 = 0.f; int cnt = 0; int cur = bseg[0];
            for (int k = 0; k < 64; ++k) {
                int g = bseg[k];
                if (g < 0) break;
                if (g != cur) {
                    atomicAdd(sums + cur * H + j, acc0);
                    if (j == 0) atomicAdd(counts + cur, (float)cnt);
                    acc0 = 0.f; cnt = 0; cur = g;
                }
                acc0 += zT[k * PAD + j];
                cnt++;
            }
            if (cnt > 0) {
                atomicAdd(sums + cur * H + j, acc0);
                if (j == 0) atomicAdd(counts + cur, (float)cnt);
            }
        }
    }
}

__global__ void div_kernel(const float* __restrict__ sums,
                           const float* __restrict__ counts,
                           float* __restrict__ out)
{
    int g = blockIdx.x, j = threadIdx.x;
    out[g * H + j] = sums[g * H + j] / fmaxf(counts[g], 1.0f);
}

extern "C" void kernel_launch(void* const* d_in, const int* in_sizes, int n_in,
                              void* d_out, int out_size, void* d_ws, size_t ws_size,
                              hipStream_t stream)
{
    const float* x     = (const float*)d_in[0];
    const int*   ei    = (const int*)d_in[1];
    const float* eattr = (const float*)d_in[2];
    const int*   batch = (const int*)d_in[3];
    const float* ne_w  = (const float*)d_in[4];
    const float* ne_b  = (const float*)d_in[5];
    const float* ee_w  = (const float*)d_in[6];
    const float* ee_b  = (const float*)d_in[7];
    const float* c1w1  = (const float*)d_in[8];
    const float* c1b1  = (const float*)d_in[9];
    const float* c1w2  = (const float*)d_in[10];
    const float* c1b2  = (const float*)d_in[11];
    const float* c2w1  = (const float*)d_in[12];
    const float* c2b1  = (const float*)d_in[13];
    const float* c2w2  = (const float*)d_in[14];
    const float* c2b2  = (const float*)d_in[15];

    const int N = in_sizes[0];
    const int E = in_sizes[2];
    const int NB = (N + 63) >> BSH;

    // ---- workspace (byte carve; sums/counts/ghist contiguous for fused zero) --
    char* w = (char*)d_ws;
    __half* h   = (__half*)w;            w += (size_t)N * H * sizeof(__half);
    __half* z   = (__half*)w;            w += (size_t)N * H * sizeof(__half);
    float* sums = (float*)w;             w += 64 * H * sizeof(float);
    float* counts = (float*)w;           w += 64 * sizeof(float);
    int* ghist  = (int*)w;               w += (size_t)NB * sizeof(int);
    int* off    = (int*)w;               w += (size_t)(NB + 1) * sizeof(int);
    int* gcur   = (int*)w;               w += (size_t)NB * sizeof(int);
    int* nstart = (int*)w;               w += (size_t)N * sizeof(int);
    int* nend   = (int*)w;               w += (size_t)N * sizeof(int);
    uintptr_t p = ((uintptr_t)w + 15) & ~(uintptr_t)15;
    int2* bed   = (int2*)p;              // E records (+16 over-read pad)

    const int eGrid = (E + EPB - 1) / EPB;
    const int mlpGrid = (N + 63) / 64;

    size_t histLds = (size_t)NB * sizeof(int);
    size_t scatLds = (size_t)(2 * EPB + (NB + 1) + NB + 256) * sizeof(int);

    const int zeroN = 64 * H + 64 + NB;
    encode_kernel<<<(N * 16 + 255) / 256, 256, 0, stream>>>(
        x, ne_w, ne_b, h, N, (unsigned*)sums, zeroN);

    // ---- bucket build + exact CSR (once, reused by both layers) ----
    bhist_kernel<<<eGrid, 256, histLds, stream>>>(ei, ghist, E, NB);
    bscan_kernel<<<1, 256, 0, stream>>>(ghist, off, gcur, NB);
    binscatter_kernel<<<eGrid, 256, scatLds, stream>>>(ei, eattr, gcur, bed, E, NB);
    dlsort_kernel<<<NB, 256, 0, stream>>>(bed, off, nstart, nend, N, NB);

    const int gatherGrid = (N + 3) / 4;

    // ---- layer 1 ----
    gather_kernel<<<gatherGrid, 256, 0, stream>>>(h, bed, nstart, nend, ee_w, ee_b, z, N);
    mlp_kernel<<<mlpGrid, 256, 0, stream>>>(z, c1w1, c1b1, c1w2, c1b2, h,
                                            batch, sums, counts, N, 0);

    // ---- layer 2 (MLP + fused pool; no h write) ----
    gather_kernel<<<gatherGrid, 256, 0, stream>>>(h, bed, nstart, nend, ee_w, ee_b, z, N);
    mlp_kernel<<<mlpGrid, 256, 0, stream>>>(z, c2w1, c2b1, c2w2, c2b2, (__half*)nullptr,
                                            batch, sums, counts, N, 1);

    div_kernel<<<64, 64, 0, stream>>>(sums, counts, (float*)d_out);
}

// Round 15
// 179.538 us; speedup vs baseline: 1.1970x; 1.1970x over previous
//
#include <hip/hip_runtime.h>
#include <hip/hip_fp16.h>

constexpr int H = 64;
constexpr int BSH = 6;      // 64 nodes per bucket
constexpr int EPB = 4096;   // edges per binning block
constexpr int EPT = EPB / 256;  // 16 edges per thread
constexpr int US = 72;      // LDS u-tile stride in halves (144B = 9*16B, aligned)

typedef _Float16 half8 __attribute__((ext_vector_type(8)));
typedef float f32x4 __attribute__((ext_vector_type(4)));

__device__ inline unsigned pack2(float a, float b) {
    __half2 hh = __floats2half2_rn(a, b);
    return *(unsigned*)&hh;
}

// ---------------- encode: h16[n][j] = x[n]*ne_w[j]+ne_b[j]; also zeroes scratch
__global__ __launch_bounds__(256) void encode_kernel(
    const float* __restrict__ x, const float* __restrict__ nw,
    const float* __restrict__ nb, __half* __restrict__ hout, int N,
    unsigned* __restrict__ zp, int zn)
{
    int idx = blockIdx.x * 256 + threadIdx.x;
    if (idx < zn) zp[idx] = 0u;               // fused zero of sums/counts/ghist
    if (idx >= N * 16) return;
    int n = idx >> 4, c = idx & 15;
    float xv = x[n];
    float4 w = ((const float4*)nw)[c];
    float4 b = ((const float4*)nb)[c];
    uint2 r;
    r.x = pack2(fmaf(xv, w.x, b.x), fmaf(xv, w.y, b.y));
    r.y = pack2(fmaf(xv, w.z, b.z), fmaf(xv, w.w, b.w));
    ((uint2*)hout)[idx] = r;
}

// ---------------- weight pack: fp32 [64][64] -> fp16 MFMA B-fragments ---------
// frag index (tj*2+ks)*64 + lane; lane holds B[ks*32+(lane>>4)*8+m][tj*16+(lane&15)]
__global__ __launch_bounds__(512) void wpack_kernel(
    const float* __restrict__ w1, const float* __restrict__ w2,
    const float* __restrict__ w3, const float* __restrict__ w4,
    half8* __restrict__ f)
{
    const float* w = (blockIdx.x == 0) ? w1 : (blockIdx.x == 1) ? w2
                   : (blockIdx.x == 2) ? w3 : w4;
    half8* dst = f + blockIdx.x * 512;
    int t = threadIdx.x;
    int lane = t & 63, grp = t >> 6;
    int tj = grp >> 1, ks = grp & 1;
    int col = tj * 16 + (lane & 15);
    int k0 = ks * 32 + ((lane >> 4) << 3);
    half8 v;
#pragma unroll
    for (int m = 0; m < 8; ++m) v[m] = (_Float16)w[(k0 + m) * H + col];
    dst[t] = v;
}

// ---------------- bucket histogram (LDS-aggregated) ----------------
__global__ __launch_bounds__(256) void bhist_kernel(
    const int* __restrict__ ei, int* __restrict__ ghist, int E, int NB)
{
    extern __shared__ int lh[];               // NB ints
    for (int b = threadIdx.x; b < NB; b += 256) lh[b] = 0;
    __syncthreads();
    int k0 = blockIdx.x * EPB;
#pragma unroll
    for (int i = 0; i < EPT; ++i) {
        int k = k0 + threadIdx.x + i * 256;
        if (k < E) atomicAdd(&lh[ei[E + k] >> BSH], 1);
    }
    __syncthreads();
    for (int b = threadIdx.x; b < NB; b += 256)
        if (lh[b]) atomicAdd(&ghist[b], lh[b]);
}

// ---------------- single-block exclusive scan; also seeds gcur ----------------
__global__ __launch_bounds__(256) void bscan_kernel(
    const int* __restrict__ ghist, int* __restrict__ off,
    int* __restrict__ gcur, int NB)
{
    __shared__ int part[256];
    int t = threadIdx.x;
    const int C = (NB + 255) / 256;
    int loc[16];
    int s = 0;
    for (int j = 0; j < C; ++j) {
        int idx = t * C + j;
        int v = (idx < NB) ? ghist[idx] : 0;
        loc[j] = s; s += v;
    }
    part[t] = s;
    __syncthreads();
    for (int d = 1; d < 256; d <<= 1) {
        int x = (t >= d) ? part[t - d] : 0;
        __syncthreads();
        part[t] += x;
        __syncthreads();
    }
    int base = part[t] - s;
    for (int j = 0; j < C; ++j) {
        int idx = t * C + j;
        if (idx < NB) { int v = base + loc[j]; off[idx] = v; gcur[idx] = v; }
    }
    if (t == 255) off[NB] = part[255];
}

// ---------------- block-aggregated bin scatter ----------------
// Record: (dstLocal<<17 | src, ea) -- src < 2^17, dl < 64.
__global__ __launch_bounds__(256) void binscatter_kernel(
    const int* __restrict__ ei, const float* __restrict__ eattr,
    int* __restrict__ gcur, int2* __restrict__ bed, int E, int NB)
{
    extern __shared__ int smem[];
    int2* stage = (int2*)smem;                // EPB int2
    int*  A     = smem + 2 * EPB;             // NB+1
    int*  B     = A + NB + 1;                 // NB
    int*  part  = B + NB;                     // 256
    int t = threadIdx.x;
    int k0 = blockIdx.x * EPB;

    for (int b = t; b < NB + 1; b += 256) A[b] = 0;
    __syncthreads();

    int dsts[EPT];
#pragma unroll
    for (int i = 0; i < EPT; ++i) {
        int k = k0 + t + i * 256;
        dsts[i] = (k < E) ? ei[E + k] : -1;
        if (dsts[i] >= 0) atomicAdd(&A[dsts[i] >> BSH], 1);
    }
    __syncthreads();

    const int C = (NB + 255) / 256;
    int loc[16];
    int s = 0;
    for (int j = 0; j < C; ++j) {
        int idx = t * C + j;
        int v = (idx < NB) ? A[idx] : 0;
        loc[j] = s; s += v;
    }
    part[t] = s;
    __syncthreads();
    for (int d = 1; d < 256; d <<= 1) {
        int x = (t >= d) ? part[t - d] : 0;
        __syncthreads();
        part[t] += x;
        __syncthreads();
    }
    int base = part[t] - s;
    int tot = part[255];
    for (int j = 0; j < C; ++j) {
        int idx = t * C + j;
        if (idx < NB) { int e = base + loc[j]; A[idx] = e; B[idx] = e; }
    }
    if (t == 255) A[NB] = tot;
    __syncthreads();

#pragma unroll
    for (int i = 0; i < EPT; ++i) {
        if (dsts[i] >= 0) {
            int k = k0 + t + i * 256;
            int b = dsts[i] >> BSH;
            int dl = dsts[i] & 63;
            int slot = atomicAdd(&B[b], 1);
            stage[slot] = make_int2((dl << 17) | ei[k], __float_as_int(eattr[k]));
        }
    }
    __syncthreads();

    for (int b = t; b < NB; b += 256) {
        int c0 = A[b], c1 = B[b];
        if (c1 > c0) B[b] = atomicAdd(&gcur[b], c1 - c0) - c0;
    }
    __syncthreads();

    int s0 = t * EPT;
    int lo = 0, hi = NB;
    while (hi - lo > 1) { int mid = (lo + hi) >> 1; if (A[mid] <= s0) lo = mid; else hi = mid; }
    int b = lo;
#pragma unroll
    for (int i = 0; i < EPT; ++i) {
        int sl = s0 + i;
        if (sl >= tot) break;
        while (sl >= A[b + 1]) ++b;
        bed[B[b] + sl] = stage[sl];
    }
}

// ---------------- per-bucket dl counting-sort -> exact per-node CSR ----------
// Oversize fallback (unreachable at this E/NB) marks nend = ~e1 (negative).
__global__ __launch_bounds__(256) void dlsort_kernel(
    int2* __restrict__ bed, const int* __restrict__ off,
    int* __restrict__ nstart, int* __restrict__ nend, int N, int NB)
{
    __shared__ int2 stage[4096];
    __shared__ int hist[64], excl[65], cur[64];
    int t = threadIdx.x, b = blockIdx.x;
    int e0 = off[b], e1 = off[b + 1], cnt = e1 - e0;
    if (t < 64) hist[t] = 0;
    __syncthreads();

    if (cnt <= 4096) {
        for (int i = t; i < cnt; i += 256) {
            int2 r = bed[e0 + i];
            stage[i] = r;
            atomicAdd(&hist[(unsigned)r.x >> 17], 1);
        }
        __syncthreads();
        if (t == 0) {
            int s = 0;
#pragma unroll
            for (int i = 0; i < 64; ++i) { excl[i] = s; s += hist[i]; }
            excl[64] = s;
        }
        __syncthreads();
        if (t < 64) {
            cur[t] = excl[t];
            int n = b * 64 + t;
            if (n < N) { nstart[n] = e0 + excl[t]; nend[n] = e0 + excl[t + 1]; }
        }
        __syncthreads();
        for (int i = t; i < cnt; i += 256) {
            int2 r = stage[i];
            int p = atomicAdd(&cur[(unsigned)r.x >> 17], 1);
            bed[e0 + p] = r;
        }
    } else {
        int n = b * 64 + t;
        if (t < 64 && n < N) { nstart[n] = e0; nend[n] = ~e1; }  // masked marker
    }
}

// ---------------- gather v5 (proven): wave/node, masked-16-burst --------------
__global__ __launch_bounds__(256) void gather_kernel(
    const __half* __restrict__ h, const int2* __restrict__ bed,
    const int* __restrict__ nstart, const int* __restrict__ nend,
    const float* __restrict__ ew, const float* __restrict__ eb,
    __half* __restrict__ z, int N)
{
    int lane = threadIdx.x & 63;
    int wid  = threadIdx.x >> 6;
    int n = blockIdx.x * 4 + wid;
    if (n >= N) return;
    float wj = ew[lane], bj = eb[lane];
    int e  = nstart[n];
    int e1 = nend[n];
    float acc = __half2float(h[(size_t)n * H + lane]);   // self term (eps = 0)

    if (e1 >= 0) {
        while (e1 - e > 16) {
            const int2* p = bed + __builtin_amdgcn_readfirstlane(e);
            int2 r0 = p[0], r1 = p[1], r2 = p[2], r3 = p[3];
            int2 r4 = p[4], r5 = p[5], r6 = p[6], r7 = p[7];
            float v0 = __half2float(h[(size_t)(r0.x & 0x1FFFF) * H + lane]);
            float v1 = __half2float(h[(size_t)(r1.x & 0x1FFFF) * H + lane]);
            float v2 = __half2float(h[(size_t)(r2.x & 0x1FFFF) * H + lane]);
            float v3 = __half2float(h[(size_t)(r3.x & 0x1FFFF) * H + lane]);
            float v4 = __half2float(h[(size_t)(r4.x & 0x1FFFF) * H + lane]);
            float v5 = __half2float(h[(size_t)(r5.x & 0x1FFFF) * H + lane]);
            float v6 = __half2float(h[(size_t)(r6.x & 0x1FFFF) * H + lane]);
            float v7 = __half2float(h[(size_t)(r7.x & 0x1FFFF) * H + lane]);
            acc += fmaxf(fmaf(__int_as_float(r0.y), wj, bj) + v0, 0.f)
                 + fmaxf(fmaf(__int_as_float(r1.y), wj, bj) + v1, 0.f)
                 + fmaxf(fmaf(__int_as_float(r2.y), wj, bj) + v2, 0.f)
                 + fmaxf(fmaf(__int_as_float(r3.y), wj, bj) + v3, 0.f)
                 + fmaxf(fmaf(__int_as_float(r4.y), wj, bj) + v4, 0.f)
                 + fmaxf(fmaf(__int_as_float(r5.y), wj, bj) + v5, 0.f)
                 + fmaxf(fmaf(__int_as_float(r6.y), wj, bj) + v6, 0.f)
                 + fmaxf(fmaf(__int_as_float(r7.y), wj, bj) + v7, 0.f);
            e += 8;
        }
        int r = e1 - e;
        const int2* p = bed + __builtin_amdgcn_readfirstlane(e);
        int2 q0 = p[0],  q1 = p[1],  q2 = p[2],  q3 = p[3];
        int2 q4 = p[4],  q5 = p[5],  q6 = p[6],  q7 = p[7];
        int2 q8 = p[8],  q9 = p[9],  qA = p[10], qB = p[11];
        int2 qC = p[12], qD = p[13], qE = p[14], qF = p[15];
        int s0 = (0  < r) ? (q0.x & 0x1FFFF) : 0;
        int s1 = (1  < r) ? (q1.x & 0x1FFFF) : 0;
        int s2 = (2  < r) ? (q2.x & 0x1FFFF) : 0;
        int s3 = (3  < r) ? (q3.x & 0x1FFFF) : 0;
        int s4 = (4  < r) ? (q4.x & 0x1FFFF) : 0;
        int s5 = (5  < r) ? (q5.x & 0x1FFFF) : 0;
        int s6 = (6  < r) ? (q6.x & 0x1FFFF) : 0;
        int s7 = (7  < r) ? (q7.x & 0x1FFFF) : 0;
        int s8 = (8  < r) ? (q8.x & 0x1FFFF) : 0;
        int s9 = (9  < r) ? (q9.x & 0x1FFFF) : 0;
        int sA = (10 < r) ? (qA.x & 0x1FFFF) : 0;
        int sB = (11 < r) ? (qB.x & 0x1FFFF) : 0;
        int sC = (12 < r) ? (qC.x & 0x1FFFF) : 0;
        int sD = (13 < r) ? (qD.x & 0x1FFFF) : 0;
        int sE = (14 < r) ? (qE.x & 0x1FFFF) : 0;
        int sF = (15 < r) ? (qF.x & 0x1FFFF) : 0;
        float v0 = __half2float(h[(size_t)s0 * H + lane]);
        float v1 = __half2float(h[(size_t)s1 * H + lane]);
        float v2 = __half2float(h[(size_t)s2 * H + lane]);
        float v3 = __half2float(h[(size_t)s3 * H + lane]);
        float v4 = __half2float(h[(size_t)s4 * H + lane]);
        float v5 = __half2float(h[(size_t)s5 * H + lane]);
        float v6 = __half2float(h[(size_t)s6 * H + lane]);
        float v7 = __half2float(h[(size_t)s7 * H + lane]);
        float v8 = __half2float(h[(size_t)s8 * H + lane]);
        float v9 = __half2float(h[(size_t)s9 * H + lane]);
        float vA = __half2float(h[(size_t)sA * H + lane]);
        float vB = __half2float(h[(size_t)sB * H + lane]);
        float vC = __half2float(h[(size_t)sC * H + lane]);
        float vD = __half2float(h[(size_t)sD * H + lane]);
        float vE = __half2float(h[(size_t)sE * H + lane]);
        float vF = __half2float(h[(size_t)sF * H + lane]);
        float m;
        m = fmaxf(fmaf(__int_as_float(q0.y), wj, bj) + v0, 0.f); acc += (0  < r) ? m : 0.f;
        m = fmaxf(fmaf(__int_as_float(q1.y), wj, bj) + v1, 0.f); acc += (1  < r) ? m : 0.f;
        m = fmaxf(fmaf(__int_as_float(q2.y), wj, bj) + v2, 0.f); acc += (2  < r) ? m : 0.f;
        m = fmaxf(fmaf(__int_as_float(q3.y), wj, bj) + v3, 0.f); acc += (3  < r) ? m : 0.f;
        m = fmaxf(fmaf(__int_as_float(q4.y), wj, bj) + v4, 0.f); acc += (4  < r) ? m : 0.f;
        m = fmaxf(fmaf(__int_as_float(q5.y), wj, bj) + v5, 0.f); acc += (5  < r) ? m : 0.f;
        m = fmaxf(fmaf(__int_as_float(q6.y), wj, bj) + v6, 0.f); acc += (6  < r) ? m : 0.f;
        m = fmaxf(fmaf(__int_as_float(q7.y), wj, bj) + v7, 0.f); acc += (7  < r) ? m : 0.f;
        m = fmaxf(fmaf(__int_as_float(q8.y), wj, bj) + v8, 0.f); acc += (8  < r) ? m : 0.f;
        m = fmaxf(fmaf(__int_as_float(q9.y), wj, bj) + v9, 0.f); acc += (9  < r) ? m : 0.f;
        m = fmaxf(fmaf(__int_as_float(qA.y), wj, bj) + vA, 0.f); acc += (10 < r) ? m : 0.f;
        m = fmaxf(fmaf(__int_as_float(qB.y), wj, bj) + vB, 0.f); acc += (11 < r) ? m : 0.f;
        m = fmaxf(fmaf(__int_as_float(qC.y), wj, bj) + vC, 0.f); acc += (12 < r) ? m : 0.f;
        m = fmaxf(fmaf(__int_as_float(qD.y), wj, bj) + vD, 0.f); acc += (13 < r) ? m : 0.f;
        m = fmaxf(fmaf(__int_as_float(qE.y), wj, bj) + vE, 0.f); acc += (14 < r) ? m : 0.f;
        m = fmaxf(fmaf(__int_as_float(qF.y), wj, bj) + vF, 0.f); acc += (15 < r) ? m : 0.f;
    } else {
        int ef = ~e1;
        unsigned mydl = (unsigned)(n & 63);
        for (int ee = e; ee < ef; ++ee) {
            int2 r = bed[ee];
            float v = __half2float(h[(size_t)(r.x & 0x1FFFF) * H + lane]);
            float m = fmaxf(fmaf(__int_as_float(r.y), wj, bj) + v, 0.f);
            acc += (((unsigned)r.x >> 17) == mydl) ? m : 0.f;
        }
    }
    z[(size_t)n * H + lane] = __float2half(acc);
}

// ---------------- MFMA MLP: per 64-node bucket, 4 waves ----------------------
// Wave w owns node rows w*16..+15. A-frags (16x16x32 f16: lane: row=l&15,
// k=(l>>4)*8+0..7) load DIRECTLY from z (contiguous 16B) -- no staging barrier.
// B-frags prepacked by wpack. C/D layout (HW-verified m89): col=lane&15,
// row=(lane>>4)*4+reg. u goes through a 9.5KB LDS tile between matmuls.
__global__ __launch_bounds__(256) void mlp_kernel(
    const __half* __restrict__ z, const half8* __restrict__ wf,
    const float* __restrict__ b1, const float* __restrict__ b2,
    __half* __restrict__ out, const int* __restrict__ batch,
    float* __restrict__ sums, float* __restrict__ counts, int N, int doPool)
{
    __shared__ _Float16 uS[64 * US];
    __shared__ int bseg[64];
    int tid = threadIdx.x, lane = tid & 63, w = tid >> 6;
    int nb = blockIdx.x * 64;
    int lo = lane & 15, hi = lane >> 4;
    if (doPool && tid < 64) bseg[tid] = (nb + tid < N) ? batch[nb + tid] : -1;

    // ---- matmul1: A from z, B from wf[0..511] ----
    const _Float16* zp = (const _Float16*)z + (size_t)(nb + w * 16 + lo) * H + hi * 8;
    half8 a0 = *(const half8*)(zp);
    half8 a1 = *(const half8*)(zp + 32);
    const half8* w1f = wf + lane;
    f32x4 c0 = {0.f, 0.f, 0.f, 0.f}, c1 = c0, c2 = c0, c3 = c0;
    c0 = __builtin_amdgcn_mfma_f32_16x16x32_f16(a0, w1f[0 * 64], c0, 0, 0, 0);
    c0 = __builtin_amdgcn_mfma_f32_16x16x32_f16(a1, w1f[1 * 64], c0, 0, 0, 0);
    c1 = __builtin_amdgcn_mfma_f32_16x16x32_f16(a0, w1f[2 * 64], c1, 0, 0, 0);
    c1 = __builtin_amdgcn_mfma_f32_16x16x32_f16(a1, w1f[3 * 64], c1, 0, 0, 0);
    c2 = __builtin_amdgcn_mfma_f32_16x16x32_f16(a0, w1f[4 * 64], c2, 0, 0, 0);
    c2 = __builtin_amdgcn_mfma_f32_16x16x32_f16(a1, w1f[5 * 64], c2, 0, 0, 0);
    c3 = __builtin_amdgcn_mfma_f32_16x16x32_f16(a0, w1f[6 * 64], c3, 0, 0, 0);
    c3 = __builtin_amdgcn_mfma_f32_16x16x32_f16(a1, w1f[7 * 64], c3, 0, 0, 0);

    // bias + relu -> uS[node][j] fp16. node = w*16 + hi*4 + r, j = tj*16 + lo.
    float bv0 = b1[0 * 16 + lo], bv1 = b1[1 * 16 + lo];
    float bv2 = b1[2 * 16 + lo], bv3 = b1[3 * 16 + lo];
    int ur = (w * 16 + hi * 4) * US + lo;
#pragma unroll
    for (int r = 0; r < 4; ++r) {
        uS[ur + r * US + 0 * 16] = (_Float16)fmaxf(c0[r] + bv0, 0.f);
        uS[ur + r * US + 1 * 16] = (_Float16)fmaxf(c1[r] + bv1, 0.f);
        uS[ur + r * US + 2 * 16] = (_Float16)fmaxf(c2[r] + bv2, 0.f);
        uS[ur + r * US + 3 * 16] = (_Float16)fmaxf(c3[r] + bv3, 0.f);
    }
    __syncthreads();

    // ---- matmul2: A from uS, B from wf[512..1023] ----
    const _Float16* up = uS + (w * 16 + lo) * US + hi * 8;
    half8 u0 = *(const half8*)(up);
    half8 u1 = *(const half8*)(up + 32);
    const half8* w2f = wf + 512 + lane;
    f32x4 d0 = {0.f, 0.f, 0.f, 0.f}, d1 = d0, d2 = d0, d3 = d0;
    d0 = __builtin_amdgcn_mfma_f32_16x16x32_f16(u0, w2f[0 * 64], d0, 0, 0, 0);
    d0 = __builtin_amdgcn_mfma_f32_16x16x32_f16(u1, w2f[1 * 64], d0, 0, 0, 0);
    d1 = __builtin_amdgcn_mfma_f32_16x16x32_f16(u0, w2f[2 * 64], d1, 0, 0, 0);
    d1 = __builtin_amdgcn_mfma_f32_16x16x32_f16(u1, w2f[3 * 64], d1, 0, 0, 0);
    d2 = __builtin_amdgcn_mfma_f32_16x16x32_f16(u0, w2f[4 * 64], d2, 0, 0, 0);
    d2 = __builtin_amdgcn_mfma_f32_16x16x32_f16(u1, w2f[5 * 64], d2, 0, 0, 0);
    d3 = __builtin_amdgcn_mfma_f32_16x16x32_f16(u0, w2f[6 * 64], d3, 0, 0, 0);
    d3 = __builtin_amdgcn_mfma_f32_16x16x32_f16(u1, w2f[7 * 64], d3, 0, 0, 0);

    float cb0 = b2[0 * 16 + lo], cb1 = b2[1 * 16 + lo];
    float cb2 = b2[2 * 16 + lo], cb3 = b2[3 * 16 + lo];

    if (!doPool) {
        // relu + fp16 direct stores: node = nb + w*16 + hi*4 + r, j = tj*16+lo
#pragma unroll
        for (int r = 0; r < 4; ++r) {
            int n = nb + w * 16 + hi * 4 + r;
            if (n < N) {
                __half* o = out + (size_t)n * H + lo;
                o[0 * 16] = __float2half(fmaxf(d0[r] + cb0, 0.f));
                o[1 * 16] = __float2half(fmaxf(d1[r] + cb1, 0.f));
                o[2 * 16] = __float2half(fmaxf(d2[r] + cb2, 0.f));
                o[3 * 16] = __float2half(fmaxf(d3[r] + cb3, 0.f));
            }
        }
    } else {
        __syncthreads();                    // all uS reads done
#pragma unroll
        for (int r = 0; r < 4; ++r) {
            uS[ur + r * US + 0 * 16] = (_Float16)fmaxf(d0[r] + cb0, 0.f);
            uS[ur + r * US + 1 * 16] = (_Float16)fmaxf(d1[r] + cb1, 0.f);
            uS[ur + r * US + 2 * 16] = (_Float16)fmaxf(d2[r] + cb2, 0.f);
            uS[ur + r * US + 3 * 16] = (_Float16)fmaxf(d3[r] + cb3, 0.f);
        }
        __syncthreads();
        if (tid < 64) {                     // wave 0: segment pool from LDS
            int j = tid;
            float acc0 = 0.f; int cnt = 0; int cur = bseg[0];
            for (int k = 0; k < 64; ++k) {
                int g = bseg[k];
                if (g < 0) break;
                if (g != cur) {
                    atomicAdd(sums + cur * H + j, acc0);
                    if (j == 0) atomicAdd(counts + cur, (float)cnt);
                    acc0 = 0.f; cnt = 0; cur = g;
                }
                acc0 += (float)uS[k * US + j];
                cnt++;
            }
            if (cnt > 0) {
                atomicAdd(sums + cur * H + j, acc0);
                if (j == 0) atomicAdd(counts + cur, (float)cnt);
            }
        }
    }
}

__global__ void div_kernel(const float* __restrict__ sums,
                           const float* __restrict__ counts,
                           float* __restrict__ out)
{
    int g = blockIdx.x, j = threadIdx.x;
    out[g * H + j] = sums[g * H + j] / fmaxf(counts[g], 1.0f);
}

extern "C" void kernel_launch(void* const* d_in, const int* in_sizes, int n_in,
                              void* d_out, int out_size, void* d_ws, size_t ws_size,
                              hipStream_t stream)
{
    const float* x     = (const float*)d_in[0];
    const int*   ei    = (const int*)d_in[1];
    const float* eattr = (const float*)d_in[2];
    const int*   batch = (const int*)d_in[3];
    const float* ne_w  = (const float*)d_in[4];
    const float* ne_b  = (const float*)d_in[5];
    const float* ee_w  = (const float*)d_in[6];
    const float* ee_b  = (const float*)d_in[7];
    const float* c1w1  = (const float*)d_in[8];
    const float* c1b1  = (const float*)d_in[9];
    const float* c1w2  = (const float*)d_in[10];
    const float* c1b2  = (const float*)d_in[11];
    const float* c2w1  = (const float*)d_in[12];
    const float* c2b1  = (const float*)d_in[13];
    const float* c2w2  = (const float*)d_in[14];
    const float* c2b2  = (const float*)d_in[15];

    const int N = in_sizes[0];
    const int E = in_sizes[2];
    const int NB = (N + 63) >> BSH;

    // ---- workspace (byte carve; sums/counts/ghist contiguous for fused zero) --
    char* w = (char*)d_ws;
    __half* h   = (__half*)w;            w += (size_t)N * H * sizeof(__half);
    __half* z   = (__half*)w;            w += (size_t)N * H * sizeof(__half);
    float* sums = (float*)w;             w += 64 * H * sizeof(float);
    float* counts = (float*)w;           w += 64 * sizeof(float);
    int* ghist  = (int*)w;               w += (size_t)NB * sizeof(int);
    int* off    = (int*)w;               w += (size_t)(NB + 1) * sizeof(int);
    int* gcur   = (int*)w;               w += (size_t)NB * sizeof(int);
    int* nstart = (int*)w;               w += (size_t)N * sizeof(int);
    int* nend   = (int*)w;               w += (size_t)N * sizeof(int);
    uintptr_t p = ((uintptr_t)w + 15) & ~(uintptr_t)15;
    half8* wfrag = (half8*)p;            // 4 x 512 half8 = 32 KB
    p += 2048 * sizeof(half8);
    int2* bed   = (int2*)p;              // E records (+16 over-read pad)

    const int eGrid = (E + EPB - 1) / EPB;
    const int mlpGrid = (N + 63) / 64;

    size_t histLds = (size_t)NB * sizeof(int);
    size_t scatLds = (size_t)(2 * EPB + (NB + 1) + NB + 256) * sizeof(int);

    const int zeroN = 64 * H + 64 + NB;
    encode_kernel<<<(N * 16 + 255) / 256, 256, 0, stream>>>(
        x, ne_w, ne_b, h, N, (unsigned*)sums, zeroN);

    // ---- weight fragment pack + bucket build (once) ----
    wpack_kernel<<<4, 512, 0, stream>>>(c1w1, c1w2, c2w1, c2w2, wfrag);
    bhist_kernel<<<eGrid, 256, histLds, stream>>>(ei, ghist, E, NB);
    bscan_kernel<<<1, 256, 0, stream>>>(ghist, off, gcur, NB);
    binscatter_kernel<<<eGrid, 256, scatLds, stream>>>(ei, eattr, gcur, bed, E, NB);
    dlsort_kernel<<<NB, 256, 0, stream>>>(bed, off, nstart, nend, N, NB);

    const int gatherGrid = (N + 3) / 4;

    // ---- layer 1 ----
    gather_kernel<<<gatherGrid, 256, 0, stream>>>(h, bed, nstart, nend, ee_w, ee_b, z, N);
    mlp_kernel<<<mlpGrid, 256, 0, stream>>>(z, wfrag, c1b1, c1b2, h,
                                            batch, sums, counts, N, 0);

    // ---- layer 2 (MLP + fused pool; no h write) ----
    gather_kernel<<<gatherGrid, 256, 0, stream>>>(h, bed, nstart, nend, ee_w, ee_b, z, N);
    mlp_kernel<<<mlpGrid, 256, 0, stream>>>(z, wfrag + 1024, c2b1, c2b2, (__half*)nullptr,
                                            batch, sums, counts, N, 1);

    div_kernel<<<64, 64, 0, stream>>>(sums, counts, (float*)d_out);
}